// Round 8
// baseline (504.403 us; speedup 1.0000x reference)
//
#include <hip/hip_runtime.h>
#include <hip/hip_bf16.h>

typedef short bf16x8 __attribute__((ext_vector_type(8)));
typedef float f32x4 __attribute__((ext_vector_type(4)));

#define NB 16384
#define IN_DIM 512
#define HD 1024
#define NT 512
#define KTILES 48

__device__ __forceinline__ short f2b(float f) {
    __hip_bfloat16 h = __float2bfloat16(f);
    return *reinterpret_cast<short*>(&h);
}

__device__ __forceinline__ void gload16(const void* g, void* l) {
    __builtin_amdgcn_global_load_lds(
        (const __attribute__((address_space(1))) void*)g,
        (__attribute__((address_space(3))) void*)l, 16, 0, 0);
}

__device__ __forceinline__ float fexp(float x)  { return __expf(x); }
__device__ __forceinline__ float frcp(float x)  { return __builtin_amdgcn_rcpf(x); }

// ------- prepass: weights -> bf16 FRAGMENT-MAJOR tiles (for reg-direct B) ----
// wsB: [bh][kt] tile of 16KB = 16 frags (f = wn*4+g) x 64 lanes x 16B.
// frag (wn,g), lane l holds B[k = kt*32 + (l>>4)*8 + j][g*HD + bh*64 + wn*16 + (l&15)]
__global__ void prep_w(const float* __restrict__ w_w, const float* __restrict__ r_w,
                       short* __restrict__ wsB) {
    const int blk = blockIdx.x;          // bh*48 + kt
    const int kt  = blk % KTILES;
    const int bh  = blk / KTILES;
    const int t   = threadIdx.x;         // 0..255
    const int l   = t & 63;
    const int wn  = t >> 6;
    const int l15 = l & 15;
    const int kq  = (l >> 4) * 8;

    const float* src = (kt < 16) ? w_w : r_w;
    const int kbase  = (kt < 16) ? kt * 32 : (kt - 16) * 32;

    short* tile = wsB + (size_t)blk * 8192;
#pragma unroll
    for (int g = 0; g < 4; ++g) {
        const float* p = src + (size_t)(kbase + kq) * 4096 + g * HD + bh * 64 + wn * 16 + l15;
        bf16x8 o;
#pragma unroll
        for (int j = 0; j < 8; ++j) o[j] = f2b(p[(size_t)j * 4096]);
        *(bf16x8*)(tile + ((wn * 4 + g) * 64 + l) * 8) = o;
    }
}

// ------- prepass: activations -> bf16 swizzled tiles (verified r3-r7) --------
__global__ void prep_a(const float* __restrict__ x, const float* __restrict__ h_p,
                       short* __restrict__ wsA) {
    const int blk  = blockIdx.x;         // bm*48 + kt
    const int kt   = blk % KTILES;
    const int bm   = blk / KTILES;
    const int t    = threadIdx.x;        // 0..511
    const int row  = t >> 1;             // 0..255
    const int half = t & 1;
    const int grow = bm * 256 + row;

    const float* src = (kt < 16)
        ? x   + (size_t)grow * IN_DIM + kt * 32 + half * 16
        : h_p + (size_t)grow * HD     + (kt - 16) * 32 + half * 16;

    float4 a0 = ((const float4*)src)[0];
    float4 a1 = ((const float4*)src)[1];
    float4 a2 = ((const float4*)src)[2];
    float4 a3 = ((const float4*)src)[3];
    float v[16] = {a0.x,a0.y,a0.z,a0.w, a1.x,a1.y,a1.z,a1.w,
                   a2.x,a2.y,a2.z,a2.w, a3.x,a3.y,a3.z,a3.w};

    char* tile = (char*)(wsA + (size_t)blk * 8192);
    const int swz = ((row >> 1) & 3) << 4;
#pragma unroll
    for (int s = 0; s < 2; ++s) {
        bf16x8 o;
#pragma unroll
        for (int j = 0; j < 8; ++j) o[j] = f2b(v[s * 8 + j]);
        *(bf16x8*)(tile + row * 64 + ((half * 32 + s * 16) ^ swz)) = o;
    }
}

// ---------------- main: A via 4-slot LDS, B direct-to-register ---------------
template<int SLOT, int VM, bool STG, bool LDB, bool USEB1>
__device__ __forceinline__ void kstep(short* S, const short* stA, const short* ldB,
                                      int aoff, int wid,
                                      bf16x8 (&b0)[4], bf16x8 (&b1)[4],
                                      f32x4 (&acc)[8][4]) {
    asm volatile("s_waitcnt vmcnt(%0)" :: "n"(VM) : "memory");
    __builtin_amdgcn_s_barrier();
    __builtin_amdgcn_sched_barrier(0);

    bf16x8 af[8];
#pragma unroll
    for (int mi = 0; mi < 8; ++mi)
        af[mi] = *(const bf16x8*)&S[SLOT * 8192 + aoff + mi * 512];

    if constexpr (STG) {
        short* d = &S[((SLOT + 3) & 3) * 8192 + wid * 512];
        gload16(stA,        d);
        gload16(stA + 4096, d + 4096);
    }
    if constexpr (LDB) {
#pragma unroll
        for (int g = 0; g < 4; ++g) {
            bf16x8 v = *(const bf16x8*)(ldB + g * 512);
            if constexpr (USEB1) b0[g] = v; else b1[g] = v;
        }
    }
    __builtin_amdgcn_s_setprio(1);
#pragma unroll
    for (int mi = 0; mi < 8; ++mi)
#pragma unroll
        for (int g = 0; g < 4; ++g)
            acc[mi][g] = __builtin_amdgcn_mfma_f32_16x16x32_bf16(
                af[mi], USEB1 ? b1[g] : b0[g], acc[mi][g], 0, 0, 0);
    __builtin_amdgcn_s_setprio(0);
}

__global__ __launch_bounds__(NT, 2) void slstm_fused(
    const short* __restrict__ wsA, const short* __restrict__ wsB,
    const float* __restrict__ c_p, const float* __restrict__ n_p,
    const float* __restrict__ m_p, const float* __restrict__ w_b,
    const float* __restrict__ r_b, float* __restrict__ out)
{
    __shared__ __align__(16) short S[4 * 8192];   // 64 KiB: 4 A-slots of 16KB

    const int t    = threadIdx.x;
    const int lane = t & 63;
    const int wid  = t >> 6;     // 0..7
    const int wm   = wid >> 2;   // 0..1
    const int wn   = wid & 3;    // 0..3
    const int l15  = lane & 15;
    const int l4   = lane >> 4;

    const int b   = (int)blockIdx.x;   // 0..255 persistent
    const int xcd = b & 7;
    const int li  = b >> 3;            // 0..31

    const int aoff = (wm * 128 + l15) * 32 + ((l4 << 3) ^ (((l15 >> 1) & 3) << 3));

    float bias[2][4];
#pragma unroll
    for (int p = 0; p < 2; ++p) {
        const int hh = (xcd * 2 + p) * 64 + wn * 16 + l15;
#pragma unroll
        for (int g = 0; g < 4; ++g) bias[p][g] = w_b[g * HD + hh] + r_b[g * HD + hh];
    }

    bf16x8 b0[4], b1[4];
    const size_t PL = (size_t)NB * HD;

    // tile-0 prologue: stage A(0),A(1),A(2); load B(0) into b0
    {
        const short* cA = wsA + (size_t)(li * KTILES) * 8192 + wid * 512 + lane * 8;
        const short* cB = wsB + (size_t)((xcd * 2) * KTILES) * 8192 + wn * 2048 + lane * 8;
#pragma unroll
        for (int k = 0; k < 3; ++k) {
            gload16(cA + k * 8192,        &S[k * 8192 + wid * 512]);
            gload16(cA + k * 8192 + 4096, &S[k * 8192 + wid * 512 + 4096]);
        }
#pragma unroll
        for (int g = 0; g < 4; ++g) b0[g] = *(const bf16x8*)(cB + g * 512);
    }

    for (int tau = 0; tau < 4; ++tau) {
        const int bm = li + 32 * (tau >> 1);
        const int bh = xcd * 2 + (tau & 1);
        const int h  = bh * 64 + wn * 16 + l15;

        const short* cA = wsA + (size_t)(bm * KTILES) * 8192 + wid * 512 + lane * 8;
        const short* cB = wsB + (size_t)(bh * KTILES) * 8192 + wn * 2048 + lane * 8;
        const int nbm = li + 32 * (((tau + 1) & 3) >> 1);
        const int nbh = xcd * 2 + ((tau + 1) & 1);
        const short* nA = wsA + (size_t)(nbm * KTILES) * 8192 + wid * 512 + lane * 8;
        const short* nB = wsB + (size_t)(nbh * KTILES) * 8192 + wn * 2048 + lane * 8;

        f32x4 acc[8][4];
#pragma unroll
        for (int g = 0; g < 4; ++g) {
            const float bv = bias[tau & 1][g];
            const f32x4 binit = {bv, bv, bv, bv};
#pragma unroll
            for (int mi = 0; mi < 8; ++mi) acc[mi][g] = binit;
        }

        // l = 0,1,2
        if (tau == 0) {
            kstep<0, 4,true,true,false>(S, cA + 3*8192, cB + 1*8192, aoff, wid, b0, b1, acc);
            kstep<1, 8,true,true,true >(S, cA + 4*8192, cB + 2*8192, aoff, wid, b0, b1, acc);
            kstep<2,12,true,true,false>(S, cA + 5*8192, cB + 3*8192, aoff, wid, b0, b1, acc);
        } else {
            kstep<0,48,true,true,false>(S, cA + 3*8192, cB + 1*8192, aoff, wid, b0, b1, acc);
            kstep<1,48,true,true,true >(S, cA + 4*8192, cB + 2*8192, aoff, wid, b0, b1, acc);
            kstep<2,48,true,true,false>(S, cA + 5*8192, cB + 3*8192, aoff, wid, b0, b1, acc);
        }

        // l = 3..44 (slots 3,0,1,2 ... ; bufs 1,0,1,0 ...)
        const short* pSt = cA + 6 * 8192;   // stage src for l=3 (kt=6)
        const short* pLd = cB + 4 * 8192;   // B src for l=3 (kt=4)
        for (int q = 0; q < 10; ++q) {
            kstep<3,12,true,true,true >(S, pSt, pLd, aoff, wid, b0, b1, acc); pSt += 8192; pLd += 8192;
            kstep<0,12,true,true,false>(S, pSt, pLd, aoff, wid, b0, b1, acc); pSt += 8192; pLd += 8192;
            kstep<1,12,true,true,true >(S, pSt, pLd, aoff, wid, b0, b1, acc); pSt += 8192; pLd += 8192;
            kstep<2,12,true,true,false>(S, pSt, pLd, aoff, wid, b0, b1, acc); pSt += 8192; pLd += 8192;
        }
        kstep<3,12,true,true,true >(S, pSt, pLd, aoff, wid, b0, b1, acc); pSt += 8192; pLd += 8192; // l43
        kstep<0,12,true,true,false>(S, pSt, pLd, aoff, wid, b0, b1, acc); pLd += 8192;              // l44 (stages kt47)

        // l = 45,46,47: stage next tile's A(0..2); l47 loads next tile's B(0)
        if (tau < 3) {
            kstep<1,12,true ,true ,true >(S, nA,            pLd,        aoff, wid, b0, b1, acc); pLd += 8192; // l45, B(46)
            kstep<2,12,true ,true ,false>(S, nA + 8192,     pLd,        aoff, wid, b0, b1, acc);              // l46, B(47)
            kstep<3,12,true ,true ,true >(S, nA + 2 * 8192, nB,         aoff, wid, b0, b1, acc);              // l47, B(next,0)
        } else {
            kstep<1,12,false,true ,true >(S, nA,            pLd,        aoff, wid, b0, b1, acc); pLd += 8192; // l45
            kstep<2,10,false,true ,false>(S, nA,            pLd,        aoff, wid, b0, b1, acc);              // l46
            kstep<3, 8,false,false,true >(S, nA,            nB,         aoff, wid, b0, b1, acc);              // l47
        }

        // ---- fused epilogue, native transcendentals ----
#pragma unroll
        for (int mi = 0; mi < 8; ++mi) {
#pragma unroll
            for (int r = 0; r < 4; ++r) {
                const int row = bm * 256 + wm * 128 + mi * 16 + l4 * 4 + r;
                const size_t idx = (size_t)row * HD + h;
                const float ci = acc[mi][0][r];
                const float ig = acc[mi][1][r];
                const float fg = acc[mi][2][r];
                const float og = acc[mi][3][r];
                const float mp  = m_p[idx];
                const float cp  = c_p[idx];
                const float np_ = n_p[idx];
                const float e2 = fexp(-2.0f * fabsf(ci));
                const float zt = (1.0f - e2) * frcp(1.0f + e2);
                const float z  = copysignf(zt, ci);
                const float it_ = fexp(ig);
                const float mt = fmaxf(fg + mp, ig);
                const float sf = fexp(fg + mp - mt);
                const float si = fexp(ig - mt);
                const float ct = sf * cp + it_ * z;
                const float nt = sf * np_ + si;
                const float ot = frcp(1.0f + fexp(-og));
                const float ht = ot * ct * frcp(nt);
                out[idx]          = ht;
                out[PL + idx]     = ct;
                out[2 * PL + idx] = ht;
                out[3 * PL + idx] = nt;
                out[4 * PL + idx] = mt;
            }
        }
    }
}

extern "C" void kernel_launch(void* const* d_in, const int* in_sizes, int n_in,
                              void* d_out, int out_size, void* d_ws, size_t ws_size,
                              hipStream_t stream) {
    const float* x   = (const float*)d_in[0];
    const float* c_p = (const float*)d_in[1];
    const float* h_p = (const float*)d_in[2];
    const float* n_p = (const float*)d_in[3];
    const float* m_p = (const float*)d_in[4];
    const float* w_w = (const float*)d_in[5];
    const float* w_b = (const float*)d_in[6];
    const float* r_w = (const float*)d_in[7];
    const float* r_b = (const float*)d_in[8];
    float* out = (float*)d_out;

    short* wsB = (short*)d_ws;                                         // 12.58 MB
    short* wsA = (short*)((char*)d_ws + (size_t)16 * KTILES * 16384);  // 50.33 MB

    prep_w<<<dim3(16 * KTILES), 256, 0, stream>>>(w_w, r_w, wsB);
    prep_a<<<dim3(64 * KTILES), NT, 0, stream>>>(x, h_p, wsA);
    slstm_fused<<<dim3(256), NT, 0, stream>>>(wsA, wsB, c_p, n_p, m_p, w_b, r_b, out);
}

// Round 9
// 324.587 us; speedup vs baseline: 1.5540x; 1.5540x over previous
//
#include <hip/hip_runtime.h>
#include <hip/hip_bf16.h>

typedef short bf16x8 __attribute__((ext_vector_type(8)));
typedef float f32x4 __attribute__((ext_vector_type(4)));

#define NB 16384
#define IN_DIM 512
#define HD 1024
#define KTILES 48

__device__ __forceinline__ short f2b(float f) {
    __hip_bfloat16 h = __float2bfloat16(f);
    return *reinterpret_cast<short*>(&h);
}

__device__ __forceinline__ void gload16(const void* g, void* l) {
    __builtin_amdgcn_global_load_lds(
        (const __attribute__((address_space(1))) void*)g,
        (__attribute__((address_space(3))) void*)l, 16, 0, 0);
}

__device__ __forceinline__ float fexp(float x)  { return __expf(x); }
__device__ __forceinline__ float frcp(float x)  { return __builtin_amdgcn_rcpf(x); }

// ------- prepass: weights -> bf16 swizzled tiles (verified r2/r5/r6) ---------
// wsB tiles: [bh 0..15][kt 0..47] each 256 cols x 32 k bf16 (16 KB), row=64B,
// element (cid,k) at byte cid*64 + ((k*2) ^ (((cid>>1)&3)<<4))
__global__ void prep_w(const float* __restrict__ w_w, const float* __restrict__ r_w,
                       short* __restrict__ wsB) {
    const int blk = blockIdx.x;          // bh*48 + kt
    const int kt  = blk % KTILES;
    const int cid = threadIdx.x;         // 0..255
    const int bh  = blk / KTILES;
    const int g   = (cid >> 4) & 3;
    const int jh  = ((cid >> 6) << 4) | (cid & 15);
    const int gcol = g * HD + bh * 64 + jh;

    const float* src = (kt < 16) ? w_w : r_w;
    const int kbase  = (kt < 16) ? kt * 32 : (kt - 16) * 32;

    float v[32];
#pragma unroll
    for (int kk = 0; kk < 32; ++kk)
        v[kk] = src[(size_t)(kbase + kk) * 4096 + gcol];

    char* tile = (char*)(wsB + (size_t)blk * 8192);
    const int swz = ((cid >> 1) & 3) << 4;
#pragma unroll
    for (int s = 0; s < 4; ++s) {
        bf16x8 o;
#pragma unroll
        for (int j = 0; j < 8; ++j) o[j] = f2b(v[s * 8 + j]);
        *(bf16x8*)(tile + cid * 64 + ((s * 16) ^ swz)) = o;
    }
}

// ------- prepass: activations -> bf16 swizzled 128-row tiles (verified r4) ---
// wsA tiles: [bm 0..127][kt 0..47] each 128 rows x 32 k bf16 (8 KB)
__global__ void prep_a(const float* __restrict__ x, const float* __restrict__ h_p,
                       short* __restrict__ wsA) {
    const int blk  = blockIdx.x;         // bm*48 + kt
    const int kt   = blk % KTILES;
    const int bm   = blk / KTILES;
    const int t    = threadIdx.x;        // 0..255
    const int row  = t >> 1;
    const int half = t & 1;
    const int grow = bm * 128 + row;

    const float* src = (kt < 16)
        ? x   + (size_t)grow * IN_DIM + kt * 32 + half * 16
        : h_p + (size_t)grow * HD     + (kt - 16) * 32 + half * 16;

    float4 a0 = ((const float4*)src)[0];
    float4 a1 = ((const float4*)src)[1];
    float4 a2 = ((const float4*)src)[2];
    float4 a3 = ((const float4*)src)[3];
    float v[16] = {a0.x,a0.y,a0.z,a0.w, a1.x,a1.y,a1.z,a1.w,
                   a2.x,a2.y,a2.z,a2.w, a3.x,a3.y,a3.z,a3.w};

    char* tile = (char*)(wsA + (size_t)blk * 4096);
    const int swz = ((row >> 1) & 3) << 4;
#pragma unroll
    for (int s = 0; s < 2; ++s) {
        bf16x8 o;
#pragma unroll
        for (int j = 0; j < 8; ++j) o[j] = f2b(v[s * 8 + j]);
        *(bf16x8*)(tile + row * 64 + ((half * 32 + s * 16) ^ swz)) = o;
    }
}

// -------- main: 128x256 tile, 8 waves (64x64 each), 3-slot counted pipeline,
// -------- 2 blocks/CU x 4 waves/SIMD ----------------------------------------
__global__ __launch_bounds__(512, 4) void slstm_fused(
    const short* __restrict__ wsA, const short* __restrict__ wsB,
    const float* __restrict__ c_p, const float* __restrict__ n_p,
    const float* __restrict__ m_p, const float* __restrict__ w_b,
    const float* __restrict__ r_b, float* __restrict__ out)
{
    // 3 rotating slots; each slot (shorts): A [0,4096) + B [4096,12288) = 24KB
    __shared__ __align__(16) short S[3 * 12288];   // 72 KiB

    const int t    = threadIdx.x;
    const int lane = t & 63;
    const int wid  = t >> 6;     // 0..7
    const int wm   = wid >> 2;   // 0..1 : 64-row half
    const int wn   = wid & 3;    // 0..3 : 16-h group
    const int l15  = lane & 15;
    const int l4   = lane >> 4;

    // XCD swizzle: xcd = b&7 owns 2 bh strips; A strip shared by block pairs
    const int b  = (int)blockIdx.x;
    const int i  = b >> 3;
    const int bh = (b & 7) * 2 + (i & 1);   // 0..15
    const int bm = i >> 1;                  // 0..127

    const int sw   = (l4 * 8) ^ (((l15 >> 1) & 3) << 3);
    const int aoff = (wm * 64 + l15) * 32 + sw;           // + mi*512
    const int boff = 4096 + (wn * 64 + l15) * 32 + sw;    // + g*512

    const short* gA = wsA + (size_t)(bm * KTILES) * 4096 + t * 8;
    const short* gB = wsB + (size_t)(bh * KTILES) * 8192 + wid * 1024 + lane * 8;
    const int aD = t * 8;                       // A DMA dest (shorts in slot)
    const int bD = 4096 + wid * 1024 + lane * 8;

    // bias folded into accumulator init
    const int h = bh * 64 + wn * 16 + l15;
    f32x4 acc[4][4];
#pragma unroll
    for (int g = 0; g < 4; ++g) {
        const float bv = w_b[g * HD + h] + r_b[g * HD + h];
        const f32x4 binit = {bv, bv, bv, bv};
#pragma unroll
        for (int mi = 0; mi < 4; ++mi) acc[mi][g] = binit;
    }

    // prologue: stage kt0 -> slot0, kt1 -> slot1
#pragma unroll
    for (int k = 0; k < 2; ++k) {
        gload16(gA + k * 4096,       &S[k * 12288 + aD]);
        gload16(gB + k * 8192,       &S[k * 12288 + bD]);
        gload16(gB + k * 8192 + 512, &S[k * 12288 + bD + 512]);
    }

    int slot = 0;
    for (int s = 0; s < KTILES; ++s) {
        if (s == KTILES - 1) { asm volatile("s_waitcnt vmcnt(0)" ::: "memory"); }
        else                 { asm volatile("s_waitcnt vmcnt(3)" ::: "memory"); }
        __builtin_amdgcn_s_barrier();
        __builtin_amdgcn_sched_barrier(0);

        const short* Sc = &S[slot * 12288];
        bf16x8 af[4], bfr[4];
#pragma unroll
        for (int g = 0; g < 4; ++g)    bfr[g] = *(const bf16x8*)&Sc[boff + g * 512];
#pragma unroll
        for (int mi = 0; mi < 4; ++mi) af[mi] = *(const bf16x8*)&Sc[aoff + mi * 512];

        if (s < KTILES - 2) {           // stage kt s+2 into slot (slot+2)%3
            short* Sd = &S[((slot == 0) ? 2 : slot - 1) * 12288];
            const short* ga = gA + (size_t)(s + 2) * 4096;
            const short* gb = gB + (size_t)(s + 2) * 8192;
            gload16(ga,       Sd + aD);
            gload16(gb,       Sd + bD);
            gload16(gb + 512, Sd + bD + 512);
        }

        __builtin_amdgcn_s_setprio(1);
#pragma unroll
        for (int mi = 0; mi < 4; ++mi)
#pragma unroll
            for (int g = 0; g < 4; ++g)
                acc[mi][g] = __builtin_amdgcn_mfma_f32_16x16x32_bf16(
                    af[mi], bfr[g], acc[mi][g], 0, 0, 0);
        __builtin_amdgcn_s_setprio(0);

        slot = (slot == 2) ? 0 : slot + 1;
    }

    // ---- fused epilogue, native transcendentals (no barrier needed) ----
    const size_t PL = (size_t)NB * HD;
#pragma unroll
    for (int mi = 0; mi < 4; ++mi) {
#pragma unroll
        for (int r = 0; r < 4; ++r) {
            const int row = bm * 128 + wm * 64 + mi * 16 + l4 * 4 + r;
            const size_t idx = (size_t)row * HD + h;
            const float ci = acc[mi][0][r];
            const float ig = acc[mi][1][r];
            const float fg = acc[mi][2][r];
            const float og = acc[mi][3][r];
            const float mp  = m_p[idx];
            const float cp  = c_p[idx];
            const float np_ = n_p[idx];
            const float e2 = fexp(-2.0f * fabsf(ci));
            const float zt = (1.0f - e2) * frcp(1.0f + e2);
            const float z  = copysignf(zt, ci);
            const float it_ = fexp(ig);
            const float mt = fmaxf(fg + mp, ig);
            const float sf = fexp(fg + mp - mt);
            const float si = fexp(ig - mt);
            const float ct = sf * cp + it_ * z;
            const float nt = sf * np_ + si;
            const float ot = frcp(1.0f + fexp(-og));
            const float ht = ot * ct * frcp(nt);
            out[idx]          = ht;
            out[PL + idx]     = ct;
            out[2 * PL + idx] = ht;
            out[3 * PL + idx] = nt;
            out[4 * PL + idx] = mt;
        }
    }
}

extern "C" void kernel_launch(void* const* d_in, const int* in_sizes, int n_in,
                              void* d_out, int out_size, void* d_ws, size_t ws_size,
                              hipStream_t stream) {
    const float* x   = (const float*)d_in[0];
    const float* c_p = (const float*)d_in[1];
    const float* h_p = (const float*)d_in[2];
    const float* n_p = (const float*)d_in[3];
    const float* m_p = (const float*)d_in[4];
    const float* w_w = (const float*)d_in[5];
    const float* w_b = (const float*)d_in[6];
    const float* r_w = (const float*)d_in[7];
    const float* r_b = (const float*)d_in[8];
    float* out = (float*)d_out;

    short* wsB = (short*)d_ws;                                         // 12.58 MB
    short* wsA = (short*)((char*)d_ws + (size_t)16 * KTILES * 16384);  // 50.33 MB

    prep_w<<<dim3(16 * KTILES), 256, 0, stream>>>(w_w, r_w, wsB);
    prep_a<<<dim3(128 * KTILES), 256, 0, stream>>>(x, h_p, wsA);
    slstm_fused<<<dim3(2048), 512, 0, stream>>>(wsA, wsB, c_p, n_p, m_p, w_b, r_b, out);
}